// Round 1
// baseline (1755.819 us; speedup 1.0000x reference)
//
#include <hip/hip_runtime.h>
#include <hip/hip_bf16.h>
#include <stdint.h>

// ---------------- problem constants ----------------
#define D_   1024
#define H_   16
#define HD_  64
#define F_   4096
#define NL_  4
#define B_   16
#define TT_  128
#define TS_  512
#define LP_  704
#define M_   (B_*LP_)

typedef __attribute__((ext_vector_type(8)))  __bf16 bf16x8;
typedef __attribute__((ext_vector_type(4)))  float  floatx4;

typedef __attribute__((address_space(3))) void lds_void_t;
typedef const __attribute__((address_space(1))) void g_void_t;

__device__ __forceinline__ void gl2lds16(const __bf16* g, const __bf16* l) {
  __builtin_amdgcn_global_load_lds((g_void_t*)g, (lds_void_t*)l, 16, 0, 0);
}

// ---------------- lens ----------------
__global__ void lens_kernel(const int* __restrict__ tmask, const int* __restrict__ smask,
                            int* __restrict__ lens) {
  __shared__ int red[256];
  int b = blockIdx.x, t = threadIdx.x;
  int tc = 0, sc = 0;
  if (t < TT_) tc = (tmask[b*TT_ + t] == 0) ? 1 : 0;
  for (int i = t; i < TS_; i += 256) sc += (smask[b*TS_ + i] == 0) ? 1 : 0;
  red[t] = tc + (sc << 16);
  __syncthreads();
  for (int s = 128; s > 0; s >>= 1) {
    if (t < s) red[t] += red[t + s];
    __syncthreads();
  }
  if (t == 0) {
    int tl = red[0] & 0xffff, sl = red[0] >> 16;
    if (tl < 0) tl = 0; if (tl > TT_) tl = TT_;
    if (sl < 0) sl = 0; if (sl > TS_) sl = TS_;
    int Lb = 2 + tl + sl;
    if (Lb > LP_) Lb = LP_;
    lens[2*b] = tl; lens[2*b+1] = Lb;
  }
}

// ---------------- plan ----------------
// plan[0]=Mtiles128, plan[1]=Mused, plan[2+b]=off[b] (b=0..16)
__global__ void plan_kernel(const int* __restrict__ lens, int* __restrict__ plan) {
  if (threadIdx.x == 0 && blockIdx.x == 0) {
    int off = 0;
    for (int b = 0; b < B_; b++) {
      plan[2 + b] = off;
      int Lb = lens[2*b+1];
      int pad = ((Lb + 127) >> 7) << 7;
      if (pad > LP_) pad = LP_;
      off += pad;
    }
    plan[2 + B_] = off;
    plan[1] = off;
    plan[0] = (off + 127) >> 7;
  }
}

// ---------------- fp32 [R,C] -> bf16 [C,R] transpose (z-batched, out z-stride) ----------------
__global__ void transpose_kernel(const float* __restrict__ in, __bf16* __restrict__ out,
                                 int R, int C, long ozs) {
  __shared__ float tile[32][33];
  int x = threadIdx.x & 31, y0 = threadIdx.x >> 5;
  const float* inb = in + (size_t)blockIdx.z * R * C;
  __bf16* outb = out + (size_t)blockIdx.z * ozs;
  int r0 = blockIdx.y * 32, c0 = blockIdx.x * 32;
  #pragma unroll
  for (int i = 0; i < 4; i++) {
    int y = y0 + 8*i;
    tile[y][x] = inb[(size_t)(r0 + y)*C + c0 + x];
  }
  __syncthreads();
  #pragma unroll
  for (int i = 0; i < 4; i++) {
    int y = y0 + 8*i;
    outb[(size_t)(c0 + y)*R + r0 + x] = (__bf16)tile[x][y];
  }
}

// ---------------- build compacted x ----------------
__global__ void build_x_kernel(const float* __restrict__ text, const float* __restrict__ speech,
                               const float* __restrict__ cls, const float* __restrict__ sep,
                               const int* __restrict__ lens, const int* __restrict__ plan,
                               __bf16* __restrict__ xbf) {
  int b = blockIdx.y, l = blockIdx.x;
  int off = plan[2+b], padLb = plan[3+b] - off;
  if (l >= padLb) return;
  int tl = lens[2*b], Lb = lens[2*b+1];
  const float* src = nullptr;
  if (l == 0)              src = cls;
  else if (l <= tl)        src = text   + ((size_t)(l-1)*B_ + b)*D_;
  else if (l == tl + 1)    src = sep;
  else if (l < Lb)         src = speech + ((size_t)(l-2-tl)*B_ + b)*D_;
  __bf16* dst = xbf + (size_t)(off + l) * D_;
  #pragma unroll
  for (int j = 0; j < 4; j++) {
    int i = threadIdx.x + j*256;
    float v = src ? src[i] : 0.f;
    dst[i] = (__bf16)v;
  }
}

// ---------------- zero-pad rows [Mused, ceil256(Mused)) of xbf and obuf ----------------
// 256-row M-tiles may read past Mused (plan pads per-batch to 128 only); keep those rows finite-zero.
__global__ void zpad_kernel(__bf16* __restrict__ xbf, __bf16* __restrict__ obuf,
                            const int* __restrict__ plan) {
  int mused = plan[1];
  int mpad = (mused + 255) & ~255;
  int r = mused + blockIdx.x;
  if (r >= mpad) return;
  __bf16* dst = (blockIdx.y == 0 ? xbf : obuf) + (size_t)r * D_;
  #pragma unroll
  for (int j = 0; j < 4; j++) dst[threadIdx.x + j*256] = (__bf16)0.f;
}

// ---------------- 256x256 8-phase GEMM (BK=64, 8 waves 2Mx4N, T2 swizzle + counted vmcnt + setprio)
// LDS layout per tile: A[256][64] bf16 row-major (128B rows), same for B (BT[n][k]).
// Read swizzle: logical (row, colbyte c) lives at physical c ^ ((row&7)<<4); staged via
// linear LDS dest + pre-swizzled GLOBAL source column (both-sides-or-neither rule).
// Stage chunks per K-tile t: Aa = A rows {0-63,128-191}, Ab = {64-127,192-255},
// B01 = B rows 0-127, B23 = 128-255 (each 16KB = 2 global_load_lds of 8KB).
// Schedule (per tile t, phases PH1..PH4): issue Ab(t+1)@PH1, Aa(t+2)@PH2, B01(t+2)@PH3,
// B23(t+2)@PH4; vmcnt(6) at PH4 => at each tile boundary the next tile's 4 chunks are landed
// while 3 chunks of t+2 stay in flight. Dests are provably dead: Aa dead after PH1 reads,
// B halves dead after PH2 (pair0 kept in regs through PH4), Ab dead after PH3.
__device__ __forceinline__ void tile_phases(
    const __bf16* AC, const __bf16* BC,
    const __bf16* gA, const __bf16* gB, int Kk,
    const __bf16* abDst, long abK, bool gAb,
    const __bf16* aaDst, long aaK,
    const __bf16* bDst,  long bK,  bool gNxt, int vmode,
    int aBase, int bBase, int swzk0, int swzk1, int ldst,
    floatx4 (&acc)[8][4])
{
  bf16x8 a[4][2], b0[2][2], b1[2][2];
  // ---- PH1: read Aa quads + B pair0; stage Ab(t+1)
  #pragma unroll
  for (int j = 0; j < 4; ++j) {
    a[j][0] = *(const bf16x8*)(AC + aBase + j*1024 + swzk0);
    a[j][1] = *(const bf16x8*)(AC + aBase + j*1024 + swzk1);
  }
  #pragma unroll
  for (int n = 0; n < 2; ++n) {
    b0[n][0] = *(const bf16x8*)(BC + bBase + n*1024 + swzk0);
    b0[n][1] = *(const bf16x8*)(BC + bBase + n*1024 + swzk1);
  }
  if (gAb) {
    gl2lds16(gA + 64*(long)Kk  + abK, abDst + 64*64  + ldst);
    gl2lds16(gA + 192*(long)Kk + abK, abDst + 192*64 + ldst);
  }
  __builtin_amdgcn_s_barrier();
  asm volatile("s_waitcnt lgkmcnt(0)" ::: "memory");
  __builtin_amdgcn_sched_barrier(0);
  __builtin_amdgcn_s_setprio(1);
  #pragma unroll
  for (int j = 0; j < 4; ++j)
    #pragma unroll
    for (int n = 0; n < 2; ++n) {
      acc[j][n] = __builtin_amdgcn_mfma_f32_16x16x32_bf16(a[j][0], b0[n][0], acc[j][n], 0, 0, 0);
      acc[j][n] = __builtin_amdgcn_mfma_f32_16x16x32_bf16(a[j][1], b0[n][1], acc[j][n], 0, 0, 0);
    }
  __builtin_amdgcn_s_setprio(0);
  __builtin_amdgcn_s_barrier();
  // ---- PH2: read B pair1; stage Aa(t+2)
  #pragma unroll
  for (int n = 0; n < 2; ++n) {
    b1[n][0] = *(const bf16x8*)(BC + bBase + (2+n)*1024 + swzk0);
    b1[n][1] = *(const bf16x8*)(BC + bBase + (2+n)*1024 + swzk1);
  }
  if (gNxt) {
    gl2lds16(gA + aaK,                aaDst + ldst);
    gl2lds16(gA + 128*(long)Kk + aaK, aaDst + 128*64 + ldst);
  }
  __builtin_amdgcn_s_barrier();
  asm volatile("s_waitcnt lgkmcnt(0)" ::: "memory");
  __builtin_amdgcn_sched_barrier(0);
  __builtin_amdgcn_s_setprio(1);
  #pragma unroll
  for (int j = 0; j < 4; ++j)
    #pragma unroll
    for (int n = 0; n < 2; ++n) {
      acc[j][2+n] = __builtin_amdgcn_mfma_f32_16x16x32_bf16(a[j][0], b1[n][0], acc[j][2+n], 0, 0, 0);
      acc[j][2+n] = __builtin_amdgcn_mfma_f32_16x16x32_bf16(a[j][1], b1[n][1], acc[j][2+n], 0, 0, 0);
    }
  __builtin_amdgcn_s_setprio(0);
  __builtin_amdgcn_s_barrier();
  // ---- PH3: read Ab quads (overwrite a); stage B01(t+2)
  #pragma unroll
  for (int j = 0; j < 4; ++j) {
    a[j][0] = *(const bf16x8*)(AC + aBase + 4096 + j*1024 + swzk0);
    a[j][1] = *(const bf16x8*)(AC + aBase + 4096 + j*1024 + swzk1);
  }
  if (gNxt) {
    gl2lds16(gB + bK,                bDst + ldst);
    gl2lds16(gB + 64*(long)Kk + bK,  bDst + 64*64 + ldst);
  }
  __builtin_amdgcn_s_barrier();
  asm volatile("s_waitcnt lgkmcnt(0)" ::: "memory");
  __builtin_amdgcn_sched_barrier(0);
  __builtin_amdgcn_s_setprio(1);
  #pragma unroll
  for (int j = 0; j < 4; ++j)
    #pragma unroll
    for (int n = 0; n < 2; ++n) {
      acc[4+j][2+n] = __builtin_amdgcn_mfma_f32_16x16x32_bf16(a[j][0], b1[n][0], acc[4+j][2+n], 0, 0, 0);
      acc[4+j][2+n] = __builtin_amdgcn_mfma_f32_16x16x32_bf16(a[j][1], b1[n][1], acc[4+j][2+n], 0, 0, 0);
    }
  __builtin_amdgcn_s_setprio(0);
  __builtin_amdgcn_s_barrier();
  // ---- PH4: stage B23(t+2); counted vmcnt; MFMA with kept b0
  if (gNxt) {
    gl2lds16(gB + 128*(long)Kk + bK, bDst + 128*64 + ldst);
    gl2lds16(gB + 192*(long)Kk + bK, bDst + 192*64 + ldst);
  }
  if (vmode == 6)      asm volatile("s_waitcnt vmcnt(6)" ::: "memory");
  else if (vmode == 0) asm volatile("s_waitcnt vmcnt(0)" ::: "memory");
  __builtin_amdgcn_s_barrier();
  __builtin_amdgcn_s_setprio(1);
  #pragma unroll
  for (int j = 0; j < 4; ++j)
    #pragma unroll
    for (int n = 0; n < 2; ++n) {
      acc[4+j][n] = __builtin_amdgcn_mfma_f32_16x16x32_bf16(a[j][0], b0[n][0], acc[4+j][n], 0, 0, 0);
      acc[4+j][n] = __builtin_amdgcn_mfma_f32_16x16x32_bf16(a[j][1], b0[n][1], acc[4+j][n], 0, 0, 0);
    }
  __builtin_amdgcn_s_setprio(0);
  __builtin_amdgcn_s_barrier();
}

// MODE 0: fp32 out (+bias); 2: bf16+relu; 5: fused QKV epilogue (q*scale / k / v-transposed)
template<int MODE>
__global__ __launch_bounds__(512, 2)
void gemm256_kernel(const __bf16* __restrict__ A, const __bf16* __restrict__ BT,
                    const float* __restrict__ bias, const float* __restrict__ bias2,
                    const float* __restrict__ bias3, void* __restrict__ Cv,
                    const int* __restrict__ plan, int Nn, int Kk, int Kloop, float scale) {
  const int mused = plan[1];
  if ((int)blockIdx.y * 256 >= mused) return;
  __shared__ __align__(16) __bf16 smem[65536];   // 128 KiB: 2 buffers x (A 256x64 + B 256x64)
  __bf16* lA0 = smem;
  __bf16* lB0 = smem + 16384;
  __bf16* lA1 = smem + 32768;
  __bf16* lB1 = smem + 49152;
  const int tid = threadIdx.x;
  const int w = tid >> 6, l = tid & 63;
  const int wm = w >> 2, wn = w & 3;
  const long tile_m = (long)blockIdx.y * 256;
  const long tile_n = (long)blockIdx.x * 256;

  int pofs[16];
  if (MODE == 5) {
    #pragma unroll
    for (int t = 0; t < 16; ++t) pofs[t] = plan[2 + t];
  }

  // staging: thread covers row srow of each 64-row issue region; global col pre-swizzled
  const int srow = tid >> 3;
  const int scol = ((tid & 7) * 16) ^ ((srow & 7) << 4);   // bytes
  const __bf16* gA = A  + (tile_m + srow) * (long)Kk + (scol >> 1);
  const __bf16* gB = BT + (tile_n + srow) * (long)Kk + (scol >> 1);
  const int ldst = w * 512;                                 // wave-uniform LDS dest (8 rows/wave)

  // prologue: tile0 {Aa,B01,B23,Ab} + tile1 {Aa,B01,B23}; vmcnt(6) => tile0 landed
  gl2lds16(gA,                     lA0 + ldst);
  gl2lds16(gA + 128*(long)Kk,      lA0 + 128*64 + ldst);
  gl2lds16(gB,                     lB0 + ldst);
  gl2lds16(gB + 64*(long)Kk,       lB0 + 64*64  + ldst);
  gl2lds16(gB + 128*(long)Kk,      lB0 + 128*64 + ldst);
  gl2lds16(gB + 192*(long)Kk,      lB0 + 192*64 + ldst);
  gl2lds16(gA + 64*(long)Kk,       lA0 + 64*64  + ldst);
  gl2lds16(gA + 192*(long)Kk,      lA0 + 192*64 + ldst);
  gl2lds16(gA + 64,                lA1 + ldst);
  gl2lds16(gA + 128*(long)Kk + 64, lA1 + 128*64 + ldst);
  gl2lds16(gB + 64,                lB1 + ldst);
  gl2lds16(gB + 64*(long)Kk + 64,  lB1 + 64*64  + ldst);
  gl2lds16(gB + 128*(long)Kk + 64, lB1 + 128*64 + ldst);
  gl2lds16(gB + 192*(long)Kk + 64, lB1 + 192*64 + ldst);
  asm volatile("s_waitcnt vmcnt(6)" ::: "memory");
  __builtin_amdgcn_s_barrier();

  // swizzled read offsets (row&7 == l&7 for all fragments since frag row base % 16 == 0)
  const int aBase = (wm*128 + (l & 15)) * 64;
  const int bBase = (wn*64  + (l & 15)) * 64;
  const int swzk0 = (((l >> 4) * 16)      ^ ((l & 7) << 4)) >> 1;
  const int swzk1 = ((64 + (l >> 4) * 16) ^ ((l & 7) << 4)) >> 1;

  floatx4 acc[8][4] = {};

  const int NIT = Kloop >> 7;   // 2 K-tiles (128 elems of K) per iteration
  for (int it = 0; it < NIT; ++it) {
    const bool more = (it + 1 < NIT);
    const long kof = (long)it * 128;
    // tile t0 = 2*it (buffers lA0/lB0); stages: Ab(t0+1)->lA1, Aa/B(t0+2)->lA0/lB0
    tile_phases(lA0, lB0, gA, gB, Kk,
                lA1, kof + 64, true,
                lA0, kof + 128,
                lB0, kof + 128, more, more ? 6 : 0,
                aBase, bBase, swzk0, swzk1, ldst, acc);
    // tile t1 = 2*it+1 (buffers lA1/lB1); stages: Ab(t0+2)->lA0, Aa/B(t0+3)->lA1/lB1
    tile_phases(lA1, lB1, gA, gB, Kk,
                lA0, kof + 128, more,
                lA1, kof + 192,
                lB1, kof + 192, more, more ? 6 : -1,
                aBase, bBase, swzk0, swzk1, ldst, acc);
  }

  // ---------------- epilogue ----------------
  const int rl4 = (l >> 4) * 4, cl = l & 15;
  const int seg = (int)(tile_n >> 10);          // uniform per block (MODE 5)
  float* outf = (float*)Cv;
  #pragma unroll
  for (int mi = 0; mi < 8; ++mi) {
    long row0 = tile_m + wm*128 + mi*16 + rl4;
    long voff = 0;
    int bb = 0;
    if (MODE == 5) {
      #pragma unroll
      for (int t = 1; t < B_; t++) bb += (row0 >= pofs[t]) ? 1 : 0;
      voff = pofs[bb];
    }
    #pragma unroll
    for (int ni = 0; ni < 4; ++ni) {
      long col = tile_n + wn*64 + ni*16 + cl;
      float bv;
      if (MODE == 5) {
        const float* bp = (seg == 0) ? bias : (seg == 1) ? bias2 : bias3;
        bv = bp[col & 1023];
      } else {
        bv = bias[col];
      }
      #pragma unroll
      for (int r = 0; r < 4; ++r) {
        long row = row0 + r;
        float v = acc[mi][ni][r] + bv;
        if (MODE == 2) v = v > 0.f ? v : 0.f;
        if (MODE == 0)      outf[row*Nn + col] = v;
        else if (MODE == 2) ((__bf16*)Cv)[row*Nn + col] = (__bf16)v;
        else {  // MODE 5
          __bf16* base = (__bf16*)Cv;
          long c = col & 1023;
          if (seg == 0)       base[row*D_ + c] = (__bf16)(v * scale);
          else if (seg == 1)  base[(long)M_*D_ + row*D_ + c] = (__bf16)v;
          else {
            long ll = row - voff;
            if (ll < LP_)
              base[2L*M_*D_ + (((long)bb*H_ + (c>>6))*HD_ + (c&63))*LP_ + ll] = (__bf16)v;
          }
        }
      }
    }
  }
}

// ---------------- flash attention (compacted rows) ----------------
__global__ __launch_bounds__(256, 2)
void attn_kernel(const __bf16* __restrict__ qb, const __bf16* __restrict__ kb,
                 const __bf16* __restrict__ vt, __bf16* __restrict__ ob,
                 const int* __restrict__ lens, const int* __restrict__ plan) {
  int col = blockIdx.x;               // b*H + h
  int b = col >> 4;
  int off = plan[2+b];
  int padLb = plan[3+b] - off;
  if ((int)blockIdx.y * 128 >= padLb) return;
  __shared__ __bf16 Ks[64*64];
  __shared__ __bf16 Vs[64*64];
  __shared__ __bf16 Ps[4][32*72];
  int tid = threadIdx.x, w = tid >> 6, l = tid & 63;
  int Lb = lens[2*b+1];
  int q0w = blockIdx.y*128 + w*32;
  const size_t bh  = (size_t)off*D_ + (size_t)(col & 15)*HD_;
  const size_t vtb = (size_t)col * HD_ * LP_;
  int nkt = (Lb + 63) >> 6;

  bf16x8 qf[2][2];
  #pragma unroll
  for (int mi = 0; mi < 2; mi++) {
    int qr = q0w + mi*16 + (l&15);
    if (qr > padLb-1) qr = padLb-1;
    const __bf16* qp = qb + bh + (size_t)qr*D_ + (l>>4)*8;
    qf[mi][0] = *(const bf16x8*)(qp);
    qf[mi][1] = *(const bf16x8*)(qp + 32);
  }
  bf16x8 ones;
  #pragma unroll
  for (int j = 0; j < 8; j++) ones[j] = (__bf16)1.0f;

  floatx4 oacc[2][4] = {};
  floatx4 lacc[2] = {};

  for (int kt = 0; kt < nkt; kt++) {
    int kbase = kt*64;
    {
      int krow = w*16 + (l>>3);
      int cb = (l&7) ^ (krow & 7);
      const __bf16* gk = kb + bh + (size_t)(kbase + krow)*D_ + cb*8;
      const __bf16* lk = Ks + (w*16)*64;
      gl2lds16(gk,                lk);
      gl2lds16(gk + 8*(size_t)D_, lk + 8*64);
    }
    {
      int vrow = w*8 + (l>>3);
      int sb = (l&7) ^ (l>>3);
      const __bf16* gv = vt + vtb + (size_t)vrow*LP_ + kbase + sb*8;
      const __bf16* lv = Vs + (w*8)*64;
      gl2lds16(gv,                  lv);
      gl2lds16(gv + 32*(size_t)LP_, lv + 32*64);
    }
    __syncthreads();

    floatx4 s4[2][4] = {};
    #pragma unroll
    for (int ks = 0; ks < 2; ks++) {
      #pragma unroll
      for (int ni = 0; ni < 4; ni++) {
        int n = ni*16 + (l&15);
        int blk = (ks*4 + (l>>4)) ^ (n & 7);
        bf16x8 kf = *(const bf16x8*)(Ks + n*64 + blk*8);
        s4[0][ni] = __builtin_amdgcn_mfma_f32_16x16x32_bf16(qf[0][ks], kf, s4[0][ni], 0, 0, 0);
        s4[1][ni] = __builtin_amdgcn_mfma_f32_16x16x32_bf16(qf[1][ks], kf, s4[1][ni], 0, 0, 0);
      }
    }
    #pragma unroll
    for (int mi = 0; mi < 2; mi++) {
      #pragma unroll
      for (int ni = 0; ni < 4; ni++) {
        int key = kbase + ni*16 + (l&15);
        bool valid = key < Lb;
        #pragma unroll
        for (int r = 0; r < 4; r++) {
          float sv = valid ? fminf(s4[mi][ni][r], 30.f) : -1e9f;
          float p = __expf(sv);
          Ps[w][(mi*16 + (l>>4)*4 + r)*72 + ni*16 + (l&15)] = (__bf16)p;
        }
      }
    }
    #pragma unroll
    for (int ks = 0; ks < 2; ks++) {
      bf16x8 pf0 = *(const bf16x8*)(&Ps[w][(l&15)*72 + ks*32 + (l>>4)*8]);
      bf16x8 pf1 = *(const bf16x8*)(&Ps[w][(16 + (l&15))*72 + ks*32 + (l>>4)*8]);
      lacc[0] = __builtin_amdgcn_mfma_f32_16x16x32_bf16(pf0, ones, lacc[0], 0, 0, 0);
      lacc[1] = __builtin_amdgcn_mfma_f32_16x16x32_bf16(pf1, ones, lacc[1], 0, 0, 0);
      #pragma unroll
      for (int ni = 0; ni < 4; ni++) {
        int n = ni*16 + (l&15);
        int blk = (ks*4 + (l>>4)) ^ (n & 7);
        bf16x8 vf = *(const bf16x8*)(Vs + n*64 + blk*8);
        oacc[0][ni] = __builtin_amdgcn_mfma_f32_16x16x32_bf16(pf0, vf, oacc[0][ni], 0, 0, 0);
        oacc[1][ni] = __builtin_amdgcn_mfma_f32_16x16x32_bf16(pf1, vf, oacc[1][ni], 0, 0, 0);
      }
    }
    __syncthreads();
  }

  #pragma unroll
  for (int mi = 0; mi < 2; mi++) {
    #pragma unroll
    for (int ni = 0; ni < 4; ni++) {
      #pragma unroll
      for (int r = 0; r < 4; r++) {
        int qrow = q0w + mi*16 + (l>>4)*4 + r;
        if (qrow < padLb) {
          float ov = oacc[mi][ni][r] / lacc[mi][r];
          ob[bh + (size_t)qrow*D_ + ni*16 + (l&15)] = (__bf16)ov;
        }
      }
    }
  }
}

// ---------------- post-norm LN: x = LN(x + t [+ t2])*s + b ----------------
__global__ void ln_kernel(__bf16* __restrict__ x, const float* __restrict__ t,
                          const float* __restrict__ t2,
                          const float* __restrict__ sc, const float* __restrict__ bi,
                          const int* __restrict__ plan) {
  int row = blockIdx.x;
  if (row >= plan[1]) return;
  __shared__ float red[2][4];
  int tid = threadIdx.x;
  const float* tr = t + (size_t)row * D_;
  const float* tr2 = t2 ? t2 + (size_t)row * D_ : nullptr;
  __bf16* xr = x + (size_t)row * D_;
  float v[4], s1 = 0.f, s2 = 0.f;
  #pragma unroll
  for (int j = 0; j < 4; j++) {
    int i = tid + j*256;
    float val = (float)xr[i] + tr[i];
    if (tr2) val += tr2[i];
    v[j] = val; s1 += val; s2 += val*val;
  }
  #pragma unroll
  for (int off = 1; off < 64; off <<= 1) {
    s1 += __shfl_xor(s1, off, 64);
    s2 += __shfl_xor(s2, off, 64);
  }
  int w = tid >> 6, l = tid & 63;
  if (l == 0) { red[0][w] = s1; red[1][w] = s2; }
  __syncthreads();
  s1 = red[0][0] + red[0][1] + red[0][2] + red[0][3];
  s2 = red[1][0] + red[1][1] + red[1][2] + red[1][3];
  float mean = s1 * (1.f/D_);
  float var  = s2 * (1.f/D_) - mean*mean;
  float rstd = rsqrtf(var + 1e-5f);
  #pragma unroll
  for (int j = 0; j < 4; j++) {
    int i = tid + j*256;
    xr[i] = (__bf16)((v[j] - mean)*rstd*sc[i] + bi[i]);
  }
}

// ---------------- final ----------------
__global__ void out_kernel(const __bf16* __restrict__ x, const float* __restrict__ wv,
                           const int* __restrict__ plan, float* __restrict__ out) {
  __shared__ float red[4];
  int b = blockIdx.x, tid = threadIdx.x;
  const __bf16* xr = x + (size_t)plan[2+b] * D_;
  float s = 0.f;
  #pragma unroll
  for (int j = 0; j < 4; j++) {
    int i = tid + j*256;
    s += (float)xr[i] * wv[i];
  }
  #pragma unroll
  for (int off = 1; off < 64; off <<= 1) s += __shfl_xor(s, off, 64);
  int w = tid >> 6, l = tid & 63;
  if (l == 0) red[w] = s;
  __syncthreads();
  if (tid == 0) out[b] = red[0] + red[1] + red[2] + red[3];
}

// ---------------- launch ----------------
extern "C" void kernel_launch(void* const* d_in, const int* in_sizes, int n_in,
                              void* d_out, int out_size, void* d_ws, size_t ws_size,
                              hipStream_t stream) {
  (void)in_sizes; (void)n_in; (void)out_size; (void)ws_size;
  const float* text   = (const float*)d_in[0];
  const float* speech = (const float*)d_in[1];
  const int*   tmask  = (const int*)d_in[2];
  const int*   smask  = (const int*)d_in[3];
  const float* cls    = (const float*)d_in[4];
  const float* sep    = (const float*)d_in[5];
  const float* Wq     = (const float*)d_in[6];
  const float* bq     = (const float*)d_in[7];
  const float* Wk     = (const float*)d_in[8];
  const float* bk     = (const float*)d_in[9];
  const float* Wv     = (const float*)d_in[10];
  const float* bv     = (const float*)d_in[11];
  const float* Wo     = (const float*)d_in[12];
  const float* bo     = (const float*)d_in[13];
  const float* ln1s   = (const float*)d_in[14];
  const float* ln1b   = (const float*)d_in[15];
  const float* fc1w   = (const float*)d_in[16];
  const float* fc1b   = (const float*)d_in[17];
  const float* fc2w   = (const float*)d_in[18];
  const float* fc2b   = (const float*)d_in[19];
  const float* ln2s   = (const float*)d_in[20];
  const float* ln2b   = (const float*)d_in[21];
  const float* outw   = (const float*)d_in[22];

  const size_t MD = (size_t)M_ * D_;
  char* ws = (char*)d_ws;
  int*    lens = (int*)ws;
  int*    plan = (int*)(ws + 128);
  __bf16* xbf  = (__bf16*)(ws + 256);
  __bf16* act  = (__bf16*)(ws + 256 + MD*2);
  float*  tmp  = (float*) (ws + 256 + MD*2 + 4*MD*2);
  __bf16* wt   = (__bf16*)(ws + 256 + MD*2 + 4*MD*2 + MD*4);

  __bf16* qb   = act;
  __bf16* kb   = act + MD;
  __bf16* vtG  = act + 2*MD;                             // [B,H,HD,LP]
  __bf16* obuf = act + 3*MD;
  __bf16* hb   = act;                                    // [M, F] in FFN phase

  const size_t DD = (size_t)D_*D_;
  const size_t DF = (size_t)D_*F_;
  __bf16* wqkvT = wt;                                    // [NL][3*1024][1024]
  __bf16* woT   = wt + 12*DD;
  __bf16* fc1T  = wt + 16*DD;
  __bf16* fc2T  = wt + 16*DD + 4*DF;

  lens_kernel<<<B_, 256, 0, stream>>>(tmask, smask, lens);
  plan_kernel<<<1, 64, 0, stream>>>(lens, plan);

  transpose_kernel<<<dim3(D_/32, D_/32, NL_), 256, 0, stream>>>(Wq, wqkvT,        D_, D_, 3*DD);
  transpose_kernel<<<dim3(D_/32, D_/32, NL_), 256, 0, stream>>>(Wk, wqkvT + DD,   D_, D_, 3*DD);
  transpose_kernel<<<dim3(D_/32, D_/32, NL_), 256, 0, stream>>>(Wv, wqkvT + 2*DD, D_, D_, 3*DD);
  transpose_kernel<<<dim3(D_/32, D_/32, NL_), 256, 0, stream>>>(Wo, woT,  D_, D_, DD);
  transpose_kernel<<<dim3(F_/32, D_/32, NL_), 256, 0, stream>>>(fc1w, fc1T, D_, F_, DF);
  transpose_kernel<<<dim3(D_/32, F_/32, NL_), 256, 0, stream>>>(fc2w, fc2T, F_, D_, DF);

  build_x_kernel<<<dim3(LP_, B_), 256, 0, stream>>>(text, speech, cls, sep, lens, plan, xbf);
  zpad_kernel<<<dim3(128, 2), 256, 0, stream>>>(xbf, obuf, plan);

  for (int lyr = 0; lyr < NL_; lyr++) {
    // fused QKV: N=3072 packed weights; epilogue routes q(*0.125)/k/v(transposed)
    gemm256_kernel<5><<<dim3(12, M_/256), 512, 0, stream>>>(
        xbf, wqkvT + (size_t)lyr*3*DD, bq + lyr*D_, bk + lyr*D_, bv + lyr*D_,
        act, plan, 3072, D_, D_, 0.125f);
    attn_kernel<<<dim3(B_*H_, (LP_+127)/128), 256, 0, stream>>>(qb, kb, vtG, obuf, lens, plan);
    gemm256_kernel<0><<<dim3(D_/256, M_/256), 512, 0, stream>>>(
        obuf, woT + (size_t)lyr*DD, bo + lyr*D_, nullptr, nullptr, tmp, plan, D_, D_, D_, 1.f);
    ln_kernel<<<M_, 256, 0, stream>>>(xbf, tmp, nullptr, ln1s + lyr*D_, ln1b + lyr*D_, plan);
    gemm256_kernel<2><<<dim3(F_/256, M_/256), 512, 0, stream>>>(
        xbf, fc1T + (size_t)lyr*DF, fc1b + lyr*F_, nullptr, nullptr, hb, plan, F_, D_, D_, 1.f);
    gemm256_kernel<0><<<dim3(D_/256, M_/256), 512, 0, stream>>>(
        hb, fc2T + (size_t)lyr*DF, fc2b + lyr*D_, nullptr, nullptr, tmp, plan, D_, F_, F_, 1.f);
    ln_kernel<<<M_, 256, 0, stream>>>(xbf, tmp, nullptr, ln2s + lyr*D_, ln2b + lyr*D_, plan);
  }

  out_kernel<<<B_, 256, 0, stream>>>(xbf, outw, plan, (float*)d_out);
}